// Round 4
// baseline (150.935 us; speedup 1.0000x reference)
//
#include <hip/hip_runtime.h>

typedef unsigned short ushort_t;
typedef short s16x8 __attribute__((ext_vector_type(8)));   // bf16 frag vector (K=32 ops)
typedef short s16x4 __attribute__((ext_vector_type(4)));   // bf16 frag vector (K=16 ops)
typedef float f32x4 __attribute__((ext_vector_type(4)));

// Device pass has __builtin_amdgcn_mfma_f32_16x16x16bf16_1k (round-13 log:
// only HOST pass errored). __has_builtin can't see aux-target builtins in the
// host pass, so gate on __HIP_DEVICE_COMPILE__. The host-pass stub must be
// __device__ __host__ because the host pass semantically checks __global__
// bodies (round-14 error) — it never codegens for device.
#if defined(__HIP_DEVICE_COMPILE__)
#define MFMA16(a, b, c) __builtin_amdgcn_mfma_f32_16x16x16bf16_1k(a, b, c, 0, 0, 0)
#else
__device__ __host__ static inline f32x4 MFMA16(s16x4, s16x4, f32x4 c) { return c; }
#endif
#define MFMA32(a, b, c) __builtin_amdgcn_mfma_f32_16x16x32_bf16(a, b, c, 0, 0, 0)

#define DEVINL __device__ __forceinline__

// async global->LDS, 16B per lane; LDS dest = wave-uniform base + lane*16
DEVINL void gload_lds16(const void* g, void* l) {
#if defined(__HIP_DEVICE_COMPILE__)
  __builtin_amdgcn_global_load_lds((const __attribute__((address_space(1))) void*)g,
                                   (__attribute__((address_space(3))) void*)l,
                                   16, 0, 0);
#endif
}

DEVINL ushort_t f2b(float f) {           // fp32 -> bf16 RNE
  union { float f; unsigned int u; } v; v.f = f;
  unsigned int r = (v.u + 0x7fffu + ((v.u >> 16) & 1u)) >> 16;
  return (ushort_t)r;
}

DEVINL ushort_t f2b_hw(float f) {        // fp32 -> bf16 via HW v_cvt (RNE)
  union { __bf16 h; ushort_t u; } cv;
  cv.h = (__bf16)f;
  return cv.u;
}

// ---------- prep: fused {Wqkv transpose, Wout transpose, fold, x->bf16} ----------
__global__ __launch_bounds__(256) void prep_kernel(
    const float* __restrict__ Wqkv, const float* __restrict__ bq,
    const float* __restrict__ Wod, const float* __restrict__ bod,
    const float* __restrict__ Wout, const float* __restrict__ x,
    ushort_t* __restrict__ WqkvT, ushort_t* __restrict__ WoT,
    float* __restrict__ Wcomb, float* __restrict__ bcomb,
    ushort_t* __restrict__ xbf)
{
  __shared__ ushort_t tile[64 * 72];
  const int b = blockIdx.x;
  const int tid = threadIdx.x;

  if (b < 256) {
    const float* in;
    ushort_t* out;
    int N, bx, by;
    if (b < 192) { in = Wqkv; out = WqkvT; N = 1536; bx = b % 24; by = b / 24; }
    else         { in = Wout; out = WoT;   N = 512;  bx = (b - 192) % 8; by = (b - 192) / 8; }
    const int K = 512;
    const int n0 = bx * 64, k0 = by * 64;
    const int cr = tid >> 4;
    const int cc = (tid & 15) * 4;
#pragma unroll
    for (int p = 0; p < 4; p++) {
      int k = k0 + p * 16 + cr;
      float4 v = *(const float4*)(in + k * N + n0 + cc);
      ushort4 o; o.x = f2b(v.x); o.y = f2b(v.y); o.z = f2b(v.z); o.w = f2b(v.w);
      *(ushort4*)(tile + (p * 16 + cr) * 72 + cc) = o;
    }
    __syncthreads();
#pragma unroll
    for (int p = 0; p < 4; p++) {
      int n = n0 + p * 16 + cr;
      ushort4 v;
      v.x = tile[(cc + 0) * 72 + p * 16 + cr];
      v.y = tile[(cc + 1) * 72 + p * 16 + cr];
      v.z = tile[(cc + 2) * 72 + p * 16 + cr];
      v.w = tile[(cc + 3) * 72 + p * 16 + cr];
      *(ushort4*)(out + n * K + k0 + cc) = v;
    }
    return;
  }

  if (b >= 385) {
    // x -> bf16 (row-major, same RNE cvt the GEMM applied per-tile before)
    const int base = (b - 385) * 2048 + tid * 8;
    float4 v0 = *(const float4*)(x + base);
    float4 v1 = *(const float4*)(x + base + 4);
    s16x8 o;
    o[0] = (short)f2b_hw(v0.x); o[1] = (short)f2b_hw(v0.y);
    o[2] = (short)f2b_hw(v0.z); o[3] = (short)f2b_hw(v0.w);
    o[4] = (short)f2b_hw(v1.x); o[5] = (short)f2b_hw(v1.y);
    o[6] = (short)f2b_hw(v1.z); o[7] = (short)f2b_hw(v1.w);
    *(s16x8*)(xbf + base) = o;
    return;
  }

  // fold: one wave per c-row
  const int w = tid >> 6, lane = tid & 63;
  const int c = (b - 256) * 4 + w;
  if (c > 512) return;
  float a[8];
  const float* src = (c < 512) ? (Wqkv + c * 1536 + lane * 8) : (bq + lane * 8);
  float4 a0 = *(const float4*)(src);
  float4 a1 = *(const float4*)(src + 4);
  a[0]=a0.x; a[1]=a0.y; a[2]=a0.z; a[3]=a0.w;
  a[4]=a1.x; a[5]=a1.y; a[6]=a1.z; a[7]=a1.w;

  float s[16];
#pragma unroll
  for (int j = 0; j < 16; j++) s[j] = 0.f;
#pragma unroll
  for (int i = 0; i < 8; i++) {
    const float* wp = Wod + (lane * 8 + i) * 16;
#pragma unroll
    for (int j = 0; j < 16; j++) s[j] += a[i] * wp[j];
  }
#pragma unroll
  for (int mask = 1; mask < 64; mask <<= 1)
#pragma unroll
    for (int j = 0; j < 16; j++) s[j] += __shfl_xor(s[j], mask);

  if (lane < 16) {
    if (c < 512) Wcomb[c * 16 + lane] = s[lane];
    else         bcomb[lane] = s[lane] + bod[lane];
  }
}

// ------- merged qkv GEMM + od: blocks [0,384) gemm, [384,896) od -------
// GEMM staging via global_load_lds width=16 (m97 structure): zero
// staging VALU, no VGPR round-trip. A reads pre-converted xbf.
__global__ __launch_bounds__(256) void qkv_od_kernel(
    const float* __restrict__ x, const ushort_t* __restrict__ xbf,
    const ushort_t* __restrict__ WT,
    const float* __restrict__ bqkv,
    const float* __restrict__ Wcomb, const float* __restrict__ bcomb,
    const int* __restrict__ lenp,
    ushort_t* __restrict__ Qh, ushort_t* __restrict__ Kh, ushort_t* __restrict__ VT,
    float* __restrict__ params)
{
  const int blk = blockIdx.x;
  const int tid = threadIdx.x;

  if (blk >= 384) {
    // ---- od path ----
    const int w = tid >> 6, lane = tid & 63;
    const int m = (blk - 384) * 4 + w;   // 0..2047
    int li = lenp[0];
    float len = (li > 0 && li < 1048576) ? (float)li : 1024.0f;

    const float* qp = x + m * 512 + lane * 8;
    float q[8];
    float4 qa = *(const float4*)(qp);
    float4 qb = *(const float4*)(qp + 4);
    q[0]=qa.x; q[1]=qa.y; q[2]=qa.z; q[3]=qa.w;
    q[4]=qb.x; q[5]=qb.y; q[6]=qb.z; q[7]=qb.w;

    float s[16];
#pragma unroll
    for (int j = 0; j < 16; j++) s[j] = 0.f;
#pragma unroll
    for (int i = 0; i < 8; i++) {
      const float* wp = Wcomb + (lane * 8 + i) * 16;
#pragma unroll
      for (int j = 0; j < 16; j++) s[j] += q[i] * wp[j];
    }
#pragma unroll
    for (int mask = 1; mask < 64; mask <<= 1)
#pragma unroll
      for (int j = 0; j < 16; j++) s[j] += __shfl_xor(s[j], mask);

    if (lane < 8) {
      int h = lane;
      int bb = m >> 10, t = m & 1023;
      float odo = s[h] + bcomb[h];
      float odd = s[8 + h] + bcomb[8 + h];
      float offset = tanhf(odo) * len;
      float dur = len / (1.f + expf(-odd));
      float anchor = (float)t + offset;
      float start = anchor - dur, end = anchor + dur;
      float bl = floorf(start), br = ceilf(end);
      float al = floorf(anchor);
      float da = anchor - al;
      float* pp = params + ((bb * 8 + h) * 1024 + t) * 6;
      pp[0] = bl; pp[1] = br; pp[2] = al;
      pp[3] = bl - start; pp[4] = end - br; pp[5] = da;
    }
    return;
  }

  // ---- qkv gemm path ----
  __shared__ __align__(16) ushort_t As[64 * 32];
  __shared__ __align__(16) ushort_t Bs[128 * 32];
  const int lane = tid & 63, w = tid >> 6;
  const int wr = w >> 1, wc = w & 1;          // wave tile 32x64
  const int quad = lane >> 4, l16 = lane & 15;
  const int bx = blk % 12, by = blk / 12;
  const int m0 = by * 64, n0 = bx * 128;

  f32x4 acc[2][4];
#pragma unroll
  for (int i = 0; i < 2; i++)
#pragma unroll
    for (int j = 0; j < 4; j++) acc[i][j] = f32x4{0.f, 0.f, 0.f, 0.f};

  const int idx = tid * 8;
  const int ra = idx >> 5, ca = idx & 31;
  const int rb1 = (idx + 2048) >> 5, cb1 = (idx + 2048) & 31;
  const int wbase = w << 10;                  // wave-uniform LDS byte base
  char* asb  = (char*)As + wbase;
  char* bsb0 = (char*)Bs + wbase;
  char* bsb1 = (char*)Bs + 4096 + wbase;
  const ushort_t* ga  = xbf + (m0 + ra) * 512 + ca;
  const ushort_t* gb0 = WT + (n0 + ra) * 512 + ca;
  const ushort_t* gb1 = WT + (n0 + rb1) * 512 + cb1;

  for (int k0 = 0; k0 < 512; k0 += 32) {
    __syncthreads();                          // prev frag reads done
    gload_lds16(ga + k0, asb);
    gload_lds16(gb0 + k0, bsb0);
    gload_lds16(gb1 + k0, bsb1);
    __syncthreads();                          // drains vmcnt -> tiles ready

    s16x8 af[2], bfr[4];
#pragma unroll
    for (int mt = 0; mt < 2; mt++)
      af[mt] = *(const s16x8*)(As + (wr * 32 + mt * 16 + l16) * 32 + quad * 8);
#pragma unroll
    for (int nt = 0; nt < 4; nt++)
      bfr[nt] = *(const s16x8*)(Bs + (wc * 64 + nt * 16 + l16) * 32 + quad * 8);
#pragma unroll
    for (int mt = 0; mt < 2; mt++)
#pragma unroll
      for (int nt = 0; nt < 4; nt++)
        acc[mt][nt] = __builtin_amdgcn_mfma_f32_16x16x32_bf16(af[mt], bfr[nt], acc[mt][nt], 0, 0, 0);
  }

#pragma unroll
  for (int nt = 0; nt < 4; nt++) {
    int c = n0 + wc * 64 + nt * 16 + l16;
    float bias = bqkv[c];
    int which = c >> 9;
    int e = c & 511;
    int h = e >> 6, d = e & 63;
#pragma unroll
    for (int mt = 0; mt < 2; mt++) {
      int mbase = m0 + wr * 32 + mt * 16 + quad * 4;
      int bb = mbase >> 10, t = mbase & 1023;
      int bh = bb * 8 + h;
      if (which == 2) {
        ushort4 pk;
        pk.x = f2b(acc[mt][nt][0] + bias);
        pk.y = f2b(acc[mt][nt][1] + bias);
        pk.z = f2b(acc[mt][nt][2] + bias);
        pk.w = f2b(acc[mt][nt][3] + bias);
        *(ushort4*)(VT + (bh * 64 + d) * 1024 + t) = pk;
      } else {
        ushort_t* dst = (which == 0) ? Qh : Kh;
        float sc = (which == 0) ? 0.125f : 1.0f;
#pragma unroll
        for (int rr = 0; rr < 4; rr++)
          dst[(bh * 1024 + t + rr) * 64 + d] = f2b((acc[mt][nt][rr] + bias) * sc);
      }
    }
  }
}

// ------- attention v6: zero-LDS loop + register double-buffer prefetch -------
// v5 proved the direct-global fragment addressing correct (and K/V fully
// L2-resident: FETCH 3.3 MB) but put L2 latency on the S-chain. v6 issues
// tile t+1's K/V fragment loads at the top of iteration t (v3's prefetch
// discipline in registers) so the compiler's vmcnt wait lands after a full
// tile of compute. No LDS staging, no barriers in the loop; LDS = 16.9 KB
// merge overlay only; launch_bounds(256,6) -> ~6 blocks/CU (24 waves/CU,
// 1.5x v3). Barrier-free waves desynchronize -> setprio pays (m191).
__global__ __launch_bounds__(256, 6) void attn_kernel(
    const ushort_t* __restrict__ Qh, const ushort_t* __restrict__ Kh,
    const ushort_t* __restrict__ VT, const float* __restrict__ params,
    ushort_t* __restrict__ Oh)
{
  __shared__ __align__(16) float Om[64 * 65 + 64];   // merge overlay only
  const int tid = threadIdx.x;
  const int lane = tid & 63, wc = tid >> 6;          // wave = col-quarter
  const int quad = lane >> 4, l16 = lane & 15;
  const int bh = blockIdx.x;
  const int mrow = blockIdx.y * 16;

  // params per lane: row q = l16 (quads redundant by construction)
  const float* ppl = params + (bh * 1024 + mrow + l16) * 6;
  float bl = ppl[0], br = ppl[1], al = ppl[2];
  float wl = ppl[3], wr2 = ppl[4], da = ppl[5];
  bool empty = (br < 0.f) || (bl > 1023.f);
  float lo = empty ? 0.f    : fmaxf(bl, 0.f);
  float hi = empty ? 1023.f : fminf(br, 1023.f);
#pragma unroll
  for (int mask = 1; mask < 16; mask <<= 1) {
    lo = fminf(lo, __shfl_xor(lo, mask));
    hi = fmaxf(hi, __shfl_xor(hi, mask));
  }
  const int tlo = ((int)lo) >> 6, thi = ((int)hi) >> 6;   // block-uniform

  // Q fragments (B-operand, K=32): bq_i[k=quad*8+j] = Q[q=l16][i*32+quad*8+j]
  const ushort_t* qrow = Qh + (bh * 1024 + mrow + l16) * 64;
  s16x8 bq0 = *(const s16x8*)(qrow + quad * 8);
  s16x8 bq1 = *(const s16x8*)(qrow + 32 + quad * 8);

  float lr = 0.f;
  f32x4 Oacc[4];
#pragma unroll
  for (int g = 0; g < 4; g++) Oacc[g] = f32x4{0.f, 0.f, 0.f, 0.f};

  // per-lane global fragment pointers (element units), advanced per tile
  const ushort_t* kptr = Kh + (bh * 1024 + tlo * 64 + wc * 16 + l16) * 64 + quad * 8;
  const ushort_t* vptr = VT + (bh * 64 + l16) * 1024 + tlo * 64 + wc * 16 + quad * 4;

  // current-tile fragments (prefetched)
  s16x8 ck0 = *(const s16x8*)(kptr);
  s16x8 ck1 = *(const s16x8*)(kptr + 32);
  s16x4 cv0 = *(const s16x4*)(vptr);
  s16x4 cv1 = *(const s16x4*)(vptr + 16384);
  s16x4 cv2 = *(const s16x4*)(vptr + 32768);
  s16x4 cv3 = *(const s16x4*)(vptr + 49152);

  for (int tt = tlo; tt <= thi; tt++) {
    const bool more = (tt < thi);
    s16x8 nk0, nk1;
    s16x4 nv0, nv1, nv2, nv3;
    if (more) {                          // next tile's loads in flight
      nk0 = *(const s16x8*)(kptr + 4096);
      nk1 = *(const s16x8*)(kptr + 4096 + 32);
      nv0 = *(const s16x4*)(vptr + 64);
      nv1 = *(const s16x4*)(vptr + 64 + 16384);
      nv2 = *(const s16x4*)(vptr + 64 + 32768);
      nv3 = *(const s16x4*)(vptr + 64 + 49152);
    }
    kptr += 4096; vptr += 64;

    // S^T = K.Q^T : kc = wc*16 + quad*4+rr, q = l16
    f32x4 z = {0.f, 0.f, 0.f, 0.f};
    __builtin_amdgcn_s_setprio(1);
    z = MFMA32(ck0, bq0, z);
    z = MFMA32(ck1, bq1, z);
    __builtin_amdgcn_s_setprio(0);

    // softmax: lane handles q=l16, kc = cbase + quad*4 + rr
    const int cbase = tt * 64 + wc * 16;
    const float c0f = (float)cbase, c1f = c0f + 15.f;
    bool f = (bl < c0f) && (br > c1f) && ((al + 1.f < c0f) || (al > c1f));
    s16x4 pt;
    if (__all((int)f)) {
#pragma unroll
      for (int rr = 0; rr < 4; rr++) {
        float pv = __expf(z[rr]);
        lr += pv;
        pt[rr] = (short)f2b_hw(pv);
      }
    } else {
#pragma unroll
      for (int rr = 0; rr < 4; rr++) {
        float cf = (float)(cbase + quad * 4 + rr);
        float s = z[rr];                 // includes 0.125 via Qh pre-scale
        float wgt = 1.f;
        wgt += (cf == bl) ? wl : 0.f;
        wgt += (cf == br) ? wr2 : 0.f;
        wgt += (cf == al + 1.f) ? da : 0.f;
        wgt += (cf == al) ? (1.f - da) : 0.f;
        s *= wgt;
        s = (cf < bl || cf > br) ? -30.f : s;
        float pv = __expf(s);
        lr += pv;
        pt[rr] = (short)f2b_hw(pv);
      }
    }

    // O^T = V^T.P^T : A = V^T frag (register), B = pt (register P)
    __builtin_amdgcn_s_setprio(1);
    Oacc[0] = MFMA16(cv0, pt, Oacc[0]);  // D[d][q]
    Oacc[1] = MFMA16(cv1, pt, Oacc[1]);
    Oacc[2] = MFMA16(cv2, pt, Oacc[2]);
    Oacc[3] = MFMA16(cv3, pt, Oacc[3]);
    __builtin_amdgcn_s_setprio(0);

    if (more) {                          // rotate prefetch -> current
      ck0 = nk0; ck1 = nk1;
      cv0 = nv0; cv1 = nv1; cv2 = nv2; cv3 = nv3;
    }
  }

  // row-sum: each quad covered distinct kc -> reduce across quads
  lr += __shfl_xor(lr, 16);
  lr += __shfl_xor(lr, 32);

  float* lwf = Om + 64 * 65;             // [wc*16 + q]
#pragma unroll
  for (int g = 0; g < 4; g++)
#pragma unroll
    for (int rr = 0; rr < 4; rr++)
      Om[(wc * 16 + l16) * 65 + g * 16 + quad * 4 + rr] = Oacc[g][rr];
  if (quad == 0) lwf[wc * 16 + l16] = lr;
  __syncthreads();

  // merge 4 col-quarter partials (fixed m=0 -> plain sums): 16x64 / 256 thr
  const int bb = bh >> 3, h = bh & 7;
  {
    int e = tid;                          // 1024 elems, 256 threads, 4 each
#pragma unroll
    for (int it = 0; it < 4; it++, e += 256) {
      int r = e >> 6, col = e & 63;
      float lg = lwf[r] + lwf[16 + r] + lwf[32 + r] + lwf[48 + r];
      float o  = Om[r * 65 + col] + Om[(16 + r) * 65 + col]
               + Om[(32 + r) * 65 + col] + Om[(48 + r) * 65 + col];
      int t = mrow + r;
      Oh[((bb << 10) + t) * 512 + h * 64 + col] = f2b_hw(o / lg);
    }
  }
}

// ------- out GEMM: 64x64 tiles, grid (8,32)=256 blocks, async staging -------
__global__ __launch_bounds__(256) void out_gemm_kernel(
    const ushort_t* __restrict__ Oh, const ushort_t* __restrict__ WT,
    const float* __restrict__ bout, float* __restrict__ outp)
{
  __shared__ __align__(16) ushort_t As[64 * 32];
  __shared__ __align__(16) ushort_t Bs[64 * 32];
  const int tid = threadIdx.x;
  const int lane = tid & 63, w = tid >> 6;
  const int wr = w >> 1, wc = w & 1;          // wave tile 32x32
  const int quad = lane >> 4, l16 = lane & 15;
  const int m0 = blockIdx.y * 64, n0 = blockIdx.x * 64;

  f32x4 acc[2][2];
#pragma unroll
  for (int i = 0; i < 2; i++)
#pragma unroll
    for (int j = 0; j < 2; j++) acc[i][j] = f32x4{0.f, 0.f, 0.f, 0.f};

  const int idx = tid * 8;
  const int ra = idx >> 5, ca = idx & 31;
  const int wbase = w << 10;
  char* asb = (char*)As + wbase;
  char* bsb = (char*)Bs + wbase;
  const ushort_t* ga = Oh + (m0 + ra) * 512 + ca;
  const ushort_t* gb = WT + (n0 + ra) * 512 + ca;

  for (int k0 = 0; k0 < 512; k0 += 32) {
    __syncthreads();
    gload_lds16(ga + k0, asb);
    gload_lds16(gb + k0, bsb);
    __syncthreads();

    s16x8 af[2], bfr[2];
#pragma unroll
    for (int mt = 0; mt < 2; mt++)
      af[mt] = *(const s16x8*)(As + (wr * 32 + mt * 16 + l16) * 32 + quad * 8);
#pragma unroll
    for (int nt = 0; nt < 2; nt++)
      bfr[nt] = *(const s16x8*)(Bs + (wc * 32 + nt * 16 + l16) * 32 + quad * 8);
#pragma unroll
    for (int mt = 0; mt < 2; mt++)
#pragma unroll
      for (int nt = 0; nt < 2; nt++)
        acc[mt][nt] = __builtin_amdgcn_mfma_f32_16x16x32_bf16(af[mt], bfr[nt], acc[mt][nt], 0, 0, 0);
  }

#pragma unroll
  for (int nt = 0; nt < 2; nt++) {
    int c = n0 + wc * 32 + nt * 16 + l16;
    float bias = bout[c];
#pragma unroll
    for (int mt = 0; mt < 2; mt++) {
#pragma unroll
      for (int rr = 0; rr < 4; rr++) {
        int m = m0 + wr * 32 + mt * 16 + quad * 4 + rr;
        outp[m * 512 + c] = acc[mt][nt][rr] + bias;
      }
    }
  }
}

extern "C" void kernel_launch(void* const* d_in, const int* in_sizes, int n_in,
                              void* d_out, int out_size, void* d_ws, size_t ws_size,
                              hipStream_t stream)
{
  const float* x    = (const float*)d_in[0];
  const float* Wqkv = (const float*)d_in[1];
  const float* bqkv = (const float*)d_in[2];
  const float* Wod  = (const float*)d_in[3];
  const float* bod  = (const float*)d_in[4];
  const float* Wout = (const float*)d_in[5];
  const float* bout = (const float*)d_in[6];
  const int* lenp   = (const int*)d_in[7];

  char* ws = (char*)d_ws;
  ushort_t* WqkvT  = (ushort_t*)(ws);                  // 1536x512 bf16
  ushort_t* WoT    = (ushort_t*)(ws + 1572864);        // 512x512 bf16
  ushort_t* Qh     = (ushort_t*)(ws + 4194304);        // 16x1024x64 bf16 (pre-scaled 0.125)
  ushort_t* Kh     = (ushort_t*)(ws + 6291456);        // 16x1024x64 bf16
  ushort_t* VT     = (ushort_t*)(ws + 8388608);        // 16x64x1024 bf16
  ushort_t* Oh     = (ushort_t*)(ws + 10485760);       // 2048x512 bf16
  float*    Wcomb  = (float*)(ws + 12582912);          // 512x16 f32
  float*    bcomb  = (float*)(ws + 12615680);          // 16 f32
  float*    params = (float*)(ws + 12615744);          // 16x1024x6 f32
  ushort_t* xbf    = (ushort_t*)(ws + 13008960);       // 2048x512 bf16

  prep_kernel<<<897, 256, 0, stream>>>(Wqkv, bqkv, Wod, bod, Wout, x,
                                       WqkvT, WoT, Wcomb, bcomb, xbf);
  qkv_od_kernel<<<896, 256, 0, stream>>>(x, xbf, WqkvT, bqkv, Wcomb, bcomb, lenp,
                                         Qh, Kh, VT, params);
  attn_kernel<<<dim3(16, 64), 256, 0, stream>>>(Qh, Kh, VT, params, Oh);
  out_gemm_kernel<<<dim3(8, 32), 256, 0, stream>>>(Oh, WoT, bout, (float*)d_out);
}

// Round 5
// 123.102 us; speedup vs baseline: 1.2261x; 1.2261x over previous
//
#include <hip/hip_runtime.h>

typedef unsigned short ushort_t;
typedef short s16x8 __attribute__((ext_vector_type(8)));   // bf16 frag vector (K=32 ops)
typedef short s16x4 __attribute__((ext_vector_type(4)));   // bf16 frag vector (K=16 ops)
typedef float f32x4 __attribute__((ext_vector_type(4)));

// Device pass has __builtin_amdgcn_mfma_f32_16x16x16bf16_1k (round-13 log:
// only HOST pass errored). __has_builtin can't see aux-target builtins in the
// host pass, so gate on __HIP_DEVICE_COMPILE__. The host-pass stub must be
// __device__ __host__ because the host pass semantically checks __global__
// bodies (round-14 error) — it never codegens for device.
#if defined(__HIP_DEVICE_COMPILE__)
#define MFMA16(a, b, c) __builtin_amdgcn_mfma_f32_16x16x16bf16_1k(a, b, c, 0, 0, 0)
#else
__device__ __host__ static inline f32x4 MFMA16(s16x4, s16x4, f32x4 c) { return c; }
#endif

#define DEVINL __device__ __forceinline__

// async global->LDS, 16B per lane; LDS dest = wave-uniform base + lane*16
DEVINL void gload_lds16(const void* g, void* l) {
#if defined(__HIP_DEVICE_COMPILE__)
  __builtin_amdgcn_global_load_lds((const __attribute__((address_space(1))) void*)g,
                                   (__attribute__((address_space(3))) void*)l,
                                   16, 0, 0);
#endif
}

DEVINL ushort_t f2b(float f) {           // fp32 -> bf16 RNE
  union { float f; unsigned int u; } v; v.f = f;
  unsigned int r = (v.u + 0x7fffu + ((v.u >> 16) & 1u)) >> 16;
  return (ushort_t)r;
}

DEVINL ushort_t f2b_hw(float f) {        // fp32 -> bf16 via HW v_cvt (RNE)
  union { __bf16 h; ushort_t u; } cv;
  cv.h = (__bf16)f;
  return cv.u;
}

// ---------- prep: fused {Wqkv transpose, Wout transpose, fold, x->bf16} ----------
__global__ __launch_bounds__(256) void prep_kernel(
    const float* __restrict__ Wqkv, const float* __restrict__ bq,
    const float* __restrict__ Wod, const float* __restrict__ bod,
    const float* __restrict__ Wout, const float* __restrict__ x,
    ushort_t* __restrict__ WqkvT, ushort_t* __restrict__ WoT,
    float* __restrict__ Wcomb, float* __restrict__ bcomb,
    ushort_t* __restrict__ xbf)
{
  __shared__ ushort_t tile[64 * 72];
  const int b = blockIdx.x;
  const int tid = threadIdx.x;

  if (b < 256) {
    const float* in;
    ushort_t* out;
    int N, bx, by;
    if (b < 192) { in = Wqkv; out = WqkvT; N = 1536; bx = b % 24; by = b / 24; }
    else         { in = Wout; out = WoT;   N = 512;  bx = (b - 192) % 8; by = (b - 192) / 8; }
    const int K = 512;
    const int n0 = bx * 64, k0 = by * 64;
    const int cr = tid >> 4;
    const int cc = (tid & 15) * 4;
#pragma unroll
    for (int p = 0; p < 4; p++) {
      int k = k0 + p * 16 + cr;
      float4 v = *(const float4*)(in + k * N + n0 + cc);
      ushort4 o; o.x = f2b(v.x); o.y = f2b(v.y); o.z = f2b(v.z); o.w = f2b(v.w);
      *(ushort4*)(tile + (p * 16 + cr) * 72 + cc) = o;
    }
    __syncthreads();
#pragma unroll
    for (int p = 0; p < 4; p++) {
      int n = n0 + p * 16 + cr;
      ushort4 v;
      v.x = tile[(cc + 0) * 72 + p * 16 + cr];
      v.y = tile[(cc + 1) * 72 + p * 16 + cr];
      v.z = tile[(cc + 2) * 72 + p * 16 + cr];
      v.w = tile[(cc + 3) * 72 + p * 16 + cr];
      *(ushort4*)(out + n * K + k0 + cc) = v;
    }
    return;
  }

  if (b >= 385) {
    // x -> bf16 (row-major, same RNE cvt the GEMM applied per-tile before)
    const int base = (b - 385) * 2048 + tid * 8;
    float4 v0 = *(const float4*)(x + base);
    float4 v1 = *(const float4*)(x + base + 4);
    s16x8 o;
    o[0] = (short)f2b_hw(v0.x); o[1] = (short)f2b_hw(v0.y);
    o[2] = (short)f2b_hw(v0.z); o[3] = (short)f2b_hw(v0.w);
    o[4] = (short)f2b_hw(v1.x); o[5] = (short)f2b_hw(v1.y);
    o[6] = (short)f2b_hw(v1.z); o[7] = (short)f2b_hw(v1.w);
    *(s16x8*)(xbf + base) = o;
    return;
  }

  // fold: one wave per c-row
  const int w = tid >> 6, lane = tid & 63;
  const int c = (b - 256) * 4 + w;
  if (c > 512) return;
  float a[8];
  const float* src = (c < 512) ? (Wqkv + c * 1536 + lane * 8) : (bq + lane * 8);
  float4 a0 = *(const float4*)(src);
  float4 a1 = *(const float4*)(src + 4);
  a[0]=a0.x; a[1]=a0.y; a[2]=a0.z; a[3]=a0.w;
  a[4]=a1.x; a[5]=a1.y; a[6]=a1.z; a[7]=a1.w;

  float s[16];
#pragma unroll
  for (int j = 0; j < 16; j++) s[j] = 0.f;
#pragma unroll
  for (int i = 0; i < 8; i++) {
    const float* wp = Wod + (lane * 8 + i) * 16;
#pragma unroll
    for (int j = 0; j < 16; j++) s[j] += a[i] * wp[j];
  }
#pragma unroll
  for (int mask = 1; mask < 64; mask <<= 1)
#pragma unroll
    for (int j = 0; j < 16; j++) s[j] += __shfl_xor(s[j], mask);

  if (lane < 16) {
    if (c < 512) Wcomb[c * 16 + lane] = s[lane];
    else         bcomb[lane] = s[lane] + bod[lane];
  }
}

// ------- merged qkv GEMM + od: blocks [0,384) gemm, [384,896) od -------
// GEMM staging via global_load_lds width=16 (m97 structure): zero
// staging VALU, no VGPR round-trip. A reads pre-converted xbf.
__global__ __launch_bounds__(256) void qkv_od_kernel(
    const float* __restrict__ x, const ushort_t* __restrict__ xbf,
    const ushort_t* __restrict__ WT,
    const float* __restrict__ bqkv,
    const float* __restrict__ Wcomb, const float* __restrict__ bcomb,
    const int* __restrict__ lenp,
    ushort_t* __restrict__ Qh, ushort_t* __restrict__ Kh, ushort_t* __restrict__ VT,
    float* __restrict__ params)
{
  const int blk = blockIdx.x;
  const int tid = threadIdx.x;

  if (blk >= 384) {
    // ---- od path ----
    const int w = tid >> 6, lane = tid & 63;
    const int m = (blk - 384) * 4 + w;   // 0..2047
    int li = lenp[0];
    float len = (li > 0 && li < 1048576) ? (float)li : 1024.0f;

    const float* qp = x + m * 512 + lane * 8;
    float q[8];
    float4 qa = *(const float4*)(qp);
    float4 qb = *(const float4*)(qp + 4);
    q[0]=qa.x; q[1]=qa.y; q[2]=qa.z; q[3]=qa.w;
    q[4]=qb.x; q[5]=qb.y; q[6]=qb.z; q[7]=qb.w;

    float s[16];
#pragma unroll
    for (int j = 0; j < 16; j++) s[j] = 0.f;
#pragma unroll
    for (int i = 0; i < 8; i++) {
      const float* wp = Wcomb + (lane * 8 + i) * 16;
#pragma unroll
      for (int j = 0; j < 16; j++) s[j] += q[i] * wp[j];
    }
#pragma unroll
    for (int mask = 1; mask < 64; mask <<= 1)
#pragma unroll
      for (int j = 0; j < 16; j++) s[j] += __shfl_xor(s[j], mask);

    if (lane < 8) {
      int h = lane;
      int bb = m >> 10, t = m & 1023;
      float odo = s[h] + bcomb[h];
      float odd = s[8 + h] + bcomb[8 + h];
      float offset = tanhf(odo) * len;
      float dur = len / (1.f + expf(-odd));
      float anchor = (float)t + offset;
      float start = anchor - dur, end = anchor + dur;
      float bl = floorf(start), br = ceilf(end);
      float al = floorf(anchor);
      float da = anchor - al;
      float* pp = params + ((bb * 8 + h) * 1024 + t) * 6;
      pp[0] = bl; pp[1] = br; pp[2] = al;
      pp[3] = bl - start; pp[4] = end - br; pp[5] = da;
    }
    return;
  }

  // ---- qkv gemm path ----
  __shared__ __align__(16) ushort_t As[64 * 32];
  __shared__ __align__(16) ushort_t Bs[128 * 32];
  const int lane = tid & 63, w = tid >> 6;
  const int wr = w >> 1, wc = w & 1;          // wave tile 32x64
  const int quad = lane >> 4, l16 = lane & 15;
  const int bx = blk % 12, by = blk / 12;
  const int m0 = by * 64, n0 = bx * 128;

  f32x4 acc[2][4];
#pragma unroll
  for (int i = 0; i < 2; i++)
#pragma unroll
    for (int j = 0; j < 4; j++) acc[i][j] = f32x4{0.f, 0.f, 0.f, 0.f};

  const int idx = tid * 8;
  const int ra = idx >> 5, ca = idx & 31;
  const int rb1 = (idx + 2048) >> 5, cb1 = (idx + 2048) & 31;
  const int wbase = w << 10;                  // wave-uniform LDS byte base
  char* asb  = (char*)As + wbase;
  char* bsb0 = (char*)Bs + wbase;
  char* bsb1 = (char*)Bs + 4096 + wbase;
  const ushort_t* ga  = xbf + (m0 + ra) * 512 + ca;
  const ushort_t* gb0 = WT + (n0 + ra) * 512 + ca;
  const ushort_t* gb1 = WT + (n0 + rb1) * 512 + cb1;

  for (int k0 = 0; k0 < 512; k0 += 32) {
    __syncthreads();                          // prev frag reads done
    gload_lds16(ga + k0, asb);
    gload_lds16(gb0 + k0, bsb0);
    gload_lds16(gb1 + k0, bsb1);
    __syncthreads();                          // drains vmcnt -> tiles ready

    s16x8 af[2], bfr[4];
#pragma unroll
    for (int mt = 0; mt < 2; mt++)
      af[mt] = *(const s16x8*)(As + (wr * 32 + mt * 16 + l16) * 32 + quad * 8);
#pragma unroll
    for (int nt = 0; nt < 4; nt++)
      bfr[nt] = *(const s16x8*)(Bs + (wc * 64 + nt * 16 + l16) * 32 + quad * 8);
#pragma unroll
    for (int mt = 0; mt < 2; mt++)
#pragma unroll
      for (int nt = 0; nt < 4; nt++)
        acc[mt][nt] = __builtin_amdgcn_mfma_f32_16x16x32_bf16(af[mt], bfr[nt], acc[mt][nt], 0, 0, 0);
  }

#pragma unroll
  for (int nt = 0; nt < 4; nt++) {
    int c = n0 + wc * 64 + nt * 16 + l16;
    float bias = bqkv[c];
    int which = c >> 9;
    int e = c & 511;
    int h = e >> 6, d = e & 63;
#pragma unroll
    for (int mt = 0; mt < 2; mt++) {
      int mbase = m0 + wr * 32 + mt * 16 + quad * 4;
      int bb = mbase >> 10, t = mbase & 1023;
      int bh = bb * 8 + h;
      if (which == 2) {
        ushort4 pk;
        pk.x = f2b(acc[mt][nt][0] + bias);
        pk.y = f2b(acc[mt][nt][1] + bias);
        pk.z = f2b(acc[mt][nt][2] + bias);
        pk.w = f2b(acc[mt][nt][3] + bias);
        *(ushort4*)(VT + (bh * 64 + d) * 1024 + t) = pk;
      } else {
        ushort_t* dst = (which == 0) ? Qh : Kh;
        float sc = (which == 0) ? 0.125f : 1.0f;
#pragma unroll
        for (int rr = 0; rr < 4; rr++)
          dst[(bh * 1024 + t + rr) * 64 + d] = f2b((acc[mt][nt][rr] + bias) * sc);
      }
    }
  }
}

// ------- attention v7: v3 structure, 32 Q-rows share each staged tile -------
// 512 threads = 8 waves: wq = w>>2 picks Q-row group (mrow + wq*16), wc = w&3
// the col-quarter. Both groups consume the SAME staged K/V tile -> staging
// traffic, ds_writes, and barriers per unit compute all halve vs v3. Grid
// (16, 32) = 512 blocks; LDS 36.9 KB -> 2 blocks/CU x 8 waves = 16 waves/CU
// (same TLP as v3). Prefetch-into-LDS ping-pong + one barrier per tile kept
// verbatim (the compiler-proven structure; register-only pipelining fails,
// round-4). Band = union over 32 rows; out-of-band rows get the existing
// -30 masking (same mechanism v3 used within its 16 rows).
__global__ __launch_bounds__(512, 4) void attn_kernel(
    const ushort_t* __restrict__ Qh, const ushort_t* __restrict__ Kh,
    const ushort_t* __restrict__ VT, const float* __restrict__ params,
    ushort_t* __restrict__ Oh)
{
  constexpr int TS = 64 * 72;                   // one K or V tile (elems)
  __shared__ __align__(16) ushort_t KV[4 * TS]; // [p][K|V], 36.9 KB; merge overlay after loop
  __shared__ float band[16];                    // per-wave lo/hi for union

  const int tid = threadIdx.x;
  const int lane = tid & 63, w = tid >> 6;
  const int wq = w >> 2;                        // Q-row group 0/1
  const int wc = w & 3;                         // col-quarter
  const int quad = lane >> 4, l16 = lane & 15;
  const int bh = blockIdx.x;
  const int mrow = blockIdx.y * 32;
  const int qidx = mrow + wq * 16 + l16;        // this lane's Q row

  // params per lane: row q (quads redundant by construction)
  const float* ppl = params + (bh * 1024 + qidx) * 6;
  float bl = ppl[0], br = ppl[1], al = ppl[2];
  float wl = ppl[3], wr2 = ppl[4], da = ppl[5];
  bool empty = (br < 0.f) || (bl > 1023.f);
  float lo = empty ? 0.f    : fmaxf(bl, 0.f);
  float hi = empty ? 1023.f : fminf(br, 1023.f);
#pragma unroll
  for (int mask = 1; mask < 16; mask <<= 1) {
    lo = fminf(lo, __shfl_xor(lo, mask));
    hi = fmaxf(hi, __shfl_xor(hi, mask));
  }
  if (lane == 0) { band[w * 2] = lo; band[w * 2 + 1] = hi; }
  __syncthreads();
  float blo = band[0], bhi = band[1];
#pragma unroll
  for (int i = 1; i < 8; i++) {
    blo = fminf(blo, band[i * 2]);
    bhi = fmaxf(bhi, band[i * 2 + 1]);
  }
  const int tlo = ((int)blo) >> 6, thi = ((int)bhi) >> 6;   // block-uniform

  // Q fragments (B-operand): bq[i][k=quad*4+j] = Q[q][i*16+quad*4+j]
  const ushort_t* qrow = Qh + (bh * 1024 + qidx) * 64;
  s16x4 bq[4];
#pragma unroll
  for (int i = 0; i < 4; i++)
    bq[i] = *(const s16x4*)(qrow + i * 16 + quad * 4);

  float lr = 0.f;
  f32x4 Oacc[4];
#pragma unroll
  for (int g = 0; g < 4; g++) Oacc[g] = f32x4{0.f, 0.f, 0.f, 0.f};

  // staging: thread -> row tid>>3 (0..63), 8-elem segment (tid&7)*8
  const int srow = tid >> 3, sseg = (tid & 7) * 8;
  const ushort_t* kgb = Kh + (bh * 1024 + srow) * 64 + sseg;   // + r0*64
  const ushort_t* vgb = VT + (bh * 64 + srow) * 1024 + sseg;   // + r0

  s16x8 kr, vr;
  {
    const int r0 = tlo * 64;
    kr = *(const s16x8*)(kgb + r0 * 64);
    vr = *(const s16x8*)(vgb + r0);
  }
  {
    ushort_t* Kt = KV;
    ushort_t* Vt = KV + TS;
    *(s16x8*)(Kt + srow * 72 + sseg) = kr;
    *(s16x8*)(Vt + srow * 72 + sseg) = vr;
  }
  __syncthreads();

  for (int tt = tlo; tt <= thi; tt++) {
    const int p = (tt - tlo) & 1;
    ushort_t* Ktp = KV + p * 2 * TS;
    ushort_t* Vtp = KV + p * 2 * TS + TS;
    const int r0 = tt * 64;
    const bool more = (tt + 1 <= thi);

    if (more) {                          // next tile's global loads in flight
      const int r1 = (tt + 1) * 64;
      kr = *(const s16x8*)(kgb + r1 * 64);
      vr = *(const s16x8*)(vgb + r1);
    }

    // S^T = K.Q^T over this wave's 16 K-cols (kc = wc*16 + ...)
    const ushort_t* krow = Ktp + (wc * 16 + l16) * 72;
    f32x4 z = {0.f, 0.f, 0.f, 0.f};
#pragma unroll
    for (int i = 0; i < 4; i++) {
      s16x4 ak = *(const s16x4*)(krow + i * 16 + quad * 4);
      z = MFMA16(ak, bq[i], z);          // D[kc][q]
    }

    // softmax: lane handles its q row, kc = cbase + quad*4 + rr
    const int cbase = r0 + wc * 16;
    const float c0f = (float)cbase, c1f = c0f + 15.f;
    bool f = (bl < c0f) && (br > c1f) && ((al + 1.f < c0f) || (al > c1f));
    s16x4 pt;
    if (__all((int)f)) {
#pragma unroll
      for (int rr = 0; rr < 4; rr++) {
        float pv = __expf(z[rr]);
        lr += pv;
        pt[rr] = (short)f2b_hw(pv);
      }
    } else {
#pragma unroll
      for (int rr = 0; rr < 4; rr++) {
        float cf = (float)(cbase + quad * 4 + rr);
        float s = z[rr];                 // includes 0.125 via Qh pre-scale
        float wgt = 1.f;
        wgt += (cf == bl) ? wl : 0.f;
        wgt += (cf == br) ? wr2 : 0.f;
        wgt += (cf == al + 1.f) ? da : 0.f;
        wgt += (cf == al) ? (1.f - da) : 0.f;
        s *= wgt;
        s = (cf < bl || cf > br) ? -30.f : s;
        float pv = __expf(s);
        lr += pv;
        pt[rr] = (short)f2b_hw(pv);
      }
    }

    // O^T = V^T.P^T : A = V^T frag (m=d local, k=kc local), B = pt (register P!)
#pragma unroll
    for (int g = 0; g < 4; g++) {
      s16x4 av = *(const s16x4*)(Vtp + (g * 16 + l16) * 72 + wc * 16 + quad * 4);
      Oacc[g] = MFMA16(av, pt, Oacc[g]); // D[d][q]
    }

    if (more) {                          // write next tile, ONE barrier per tile
      ushort_t* Ktn = KV + (p ^ 1) * 2 * TS;
      ushort_t* Vtn = KV + (p ^ 1) * 2 * TS + TS;
      *(s16x8*)(Ktn + srow * 72 + sseg) = kr;
      *(s16x8*)(Vtn + srow * 72 + sseg) = vr;
      __syncthreads();
    }
  }

  // row-sum: each quad covered distinct kc -> reduce across quads
  lr += __shfl_xor(lr, 16);
  lr += __shfl_xor(lr, 32);

  // merge scratch overlays dead staging LDS (barrier-separated)
  __syncthreads();
  float* Om  = (float*)KV;               // [w][16 q][65]
  float* lwf = Om + 8 * 16 * 65;         // [w][16 q]
#pragma unroll
  for (int g = 0; g < 4; g++)
#pragma unroll
    for (int rr = 0; rr < 4; rr++)
      Om[(w * 16 + l16) * 65 + g * 16 + quad * 4 + rr] = Oacc[g][rr];
  if (quad == 0) lwf[w * 16 + l16] = lr;
  __syncthreads();

  // merge 4 col-quarter partials per Q-group: 32x64 elems / 512 thr
  const int bb = bh >> 3, h = bh & 7;
  {
    int e = tid;                          // 2048 elems, 512 threads, 4 each
#pragma unroll
    for (int it = 0; it < 4; it++, e += 512) {
      int r = e >> 6, col = e & 63;       // r 0..31
      int p0 = (r >> 4) * 4, rl = r & 15;
      float lg = lwf[(p0 + 0) * 16 + rl] + lwf[(p0 + 1) * 16 + rl]
               + lwf[(p0 + 2) * 16 + rl] + lwf[(p0 + 3) * 16 + rl];
      float o  = Om[((p0 + 0) * 16 + rl) * 65 + col] + Om[((p0 + 1) * 16 + rl) * 65 + col]
               + Om[((p0 + 2) * 16 + rl) * 65 + col] + Om[((p0 + 3) * 16 + rl) * 65 + col];
      int t = mrow + r;
      Oh[((bb << 10) + t) * 512 + h * 64 + col] = f2b_hw(o / lg);
    }
  }
}

// ------- out GEMM: 64x64 tiles, grid (8,32)=256 blocks, async staging -------
__global__ __launch_bounds__(256) void out_gemm_kernel(
    const ushort_t* __restrict__ Oh, const ushort_t* __restrict__ WT,
    const float* __restrict__ bout, float* __restrict__ outp)
{
  __shared__ __align__(16) ushort_t As[64 * 32];
  __shared__ __align__(16) ushort_t Bs[64 * 32];
  const int tid = threadIdx.x;
  const int lane = tid & 63, w = tid >> 6;
  const int wr = w >> 1, wc = w & 1;          // wave tile 32x32
  const int quad = lane >> 4, l16 = lane & 15;
  const int m0 = blockIdx.y * 64, n0 = blockIdx.x * 64;

  f32x4 acc[2][2];
#pragma unroll
  for (int i = 0; i < 2; i++)
#pragma unroll
    for (int j = 0; j < 2; j++) acc[i][j] = f32x4{0.f, 0.f, 0.f, 0.f};

  const int idx = tid * 8;
  const int ra = idx >> 5, ca = idx & 31;
  const int wbase = w << 10;
  char* asb = (char*)As + wbase;
  char* bsb = (char*)Bs + wbase;
  const ushort_t* ga = Oh + (m0 + ra) * 512 + ca;
  const ushort_t* gb = WT + (n0 + ra) * 512 + ca;

  for (int k0 = 0; k0 < 512; k0 += 32) {
    __syncthreads();
    gload_lds16(ga + k0, asb);
    gload_lds16(gb + k0, bsb);
    __syncthreads();

    s16x8 af[2], bfr[2];
#pragma unroll
    for (int mt = 0; mt < 2; mt++)
      af[mt] = *(const s16x8*)(As + (wr * 32 + mt * 16 + l16) * 32 + quad * 8);
#pragma unroll
    for (int nt = 0; nt < 2; nt++)
      bfr[nt] = *(const s16x8*)(Bs + (wc * 32 + nt * 16 + l16) * 32 + quad * 8);
#pragma unroll
    for (int mt = 0; mt < 2; mt++)
#pragma unroll
      for (int nt = 0; nt < 2; nt++)
        acc[mt][nt] = __builtin_amdgcn_mfma_f32_16x16x32_bf16(af[mt], bfr[nt], acc[mt][nt], 0, 0, 0);
  }

#pragma unroll
  for (int nt = 0; nt < 2; nt++) {
    int c = n0 + wc * 32 + nt * 16 + l16;
    float bias = bout[c];
#pragma unroll
    for (int mt = 0; mt < 2; mt++) {
#pragma unroll
      for (int rr = 0; rr < 4; rr++) {
        int m = m0 + wr * 32 + mt * 16 + quad * 4 + rr;
        outp[m * 512 + c] = acc[mt][nt][rr] + bias;
      }
    }
  }
}

extern "C" void kernel_launch(void* const* d_in, const int* in_sizes, int n_in,
                              void* d_out, int out_size, void* d_ws, size_t ws_size,
                              hipStream_t stream)
{
  const float* x    = (const float*)d_in[0];
  const float* Wqkv = (const float*)d_in[1];
  const float* bqkv = (const float*)d_in[2];
  const float* Wod  = (const float*)d_in[3];
  const float* bod  = (const float*)d_in[4];
  const float* Wout = (const float*)d_in[5];
  const float* bout = (const float*)d_in[6];
  const int* lenp   = (const int*)d_in[7];

  char* ws = (char*)d_ws;
  ushort_t* WqkvT  = (ushort_t*)(ws);                  // 1536x512 bf16
  ushort_t* WoT    = (ushort_t*)(ws + 1572864);        // 512x512 bf16
  ushort_t* Qh     = (ushort_t*)(ws + 4194304);        // 16x1024x64 bf16 (pre-scaled 0.125)
  ushort_t* Kh     = (ushort_t*)(ws + 6291456);        // 16x1024x64 bf16
  ushort_t* VT     = (ushort_t*)(ws + 8388608);        // 16x64x1024 bf16
  ushort_t* Oh     = (ushort_t*)(ws + 10485760);       // 2048x512 bf16
  float*    Wcomb  = (float*)(ws + 12582912);          // 512x16 f32
  float*    bcomb  = (float*)(ws + 12615680);          // 16 f32
  float*    params = (float*)(ws + 12615744);          // 16x1024x6 f32
  ushort_t* xbf    = (ushort_t*)(ws + 13008960);       // 2048x512 bf16

  prep_kernel<<<897, 256, 0, stream>>>(Wqkv, bqkv, Wod, bod, Wout, x,
                                       WqkvT, WoT, Wcomb, bcomb, xbf);
  qkv_od_kernel<<<896, 256, 0, stream>>>(x, xbf, WqkvT, bqkv, Wcomb, bcomb, lenp,
                                         Qh, Kh, VT, params);
  attn_kernel<<<dim3(16, 32), 512, 0, stream>>>(Qh, Kh, VT, params, Oh);
  out_gemm_kernel<<<dim3(8, 32), 256, 0, stream>>>(Oh, WoT, bout, (float*)d_out);
}

// Round 6
// 122.700 us; speedup vs baseline: 1.2301x; 1.0033x over previous
//
#include <hip/hip_runtime.h>

typedef unsigned short ushort_t;
typedef short s16x8 __attribute__((ext_vector_type(8)));   // bf16 frag vector (K=32 ops)
typedef short s16x4 __attribute__((ext_vector_type(4)));   // bf16 frag vector (K=16 ops)
typedef float f32x4 __attribute__((ext_vector_type(4)));

// Device pass has __builtin_amdgcn_mfma_f32_16x16x16bf16_1k (round-13 log:
// only HOST pass errored). __has_builtin can't see aux-target builtins in the
// host pass, so gate on __HIP_DEVICE_COMPILE__. The host-pass stub must be
// __device__ __host__ because the host pass semantically checks __global__
// bodies (round-14 error) — it never codegens for device.
#if defined(__HIP_DEVICE_COMPILE__)
#define MFMA16(a, b, c) __builtin_amdgcn_mfma_f32_16x16x16bf16_1k(a, b, c, 0, 0, 0)
#else
__device__ __host__ static inline f32x4 MFMA16(s16x4, s16x4, f32x4 c) { return c; }
#endif
#define MFMA32(a, b, c) __builtin_amdgcn_mfma_f32_16x16x32_bf16(a, b, c, 0, 0, 0)

#define DEVINL __device__ __forceinline__

// async global->LDS, 16B per lane; LDS dest = wave-uniform base + lane*16
DEVINL void gload_lds16(const void* g, void* l) {
#if defined(__HIP_DEVICE_COMPILE__)
  __builtin_amdgcn_global_load_lds((const __attribute__((address_space(1))) void*)g,
                                   (__attribute__((address_space(3))) void*)l,
                                   16, 0, 0);
#endif
}

DEVINL ushort_t f2b(float f) {           // fp32 -> bf16 RNE
  union { float f; unsigned int u; } v; v.f = f;
  unsigned int r = (v.u + 0x7fffu + ((v.u >> 16) & 1u)) >> 16;
  return (ushort_t)r;
}

DEVINL ushort_t f2b_hw(float f) {        // fp32 -> bf16 via HW v_cvt (RNE)
  union { __bf16 h; ushort_t u; } cv;
  cv.h = (__bf16)f;
  return cv.u;
}

// ---------- prep: fused {Wqkv transpose, Wout transpose, fold, x->bf16} ----------
__global__ __launch_bounds__(256) void prep_kernel(
    const float* __restrict__ Wqkv, const float* __restrict__ bq,
    const float* __restrict__ Wod, const float* __restrict__ bod,
    const float* __restrict__ Wout, const float* __restrict__ x,
    ushort_t* __restrict__ WqkvT, ushort_t* __restrict__ WoT,
    float* __restrict__ Wcomb, float* __restrict__ bcomb,
    ushort_t* __restrict__ xbf)
{
  __shared__ ushort_t tile[64 * 72];
  const int b = blockIdx.x;
  const int tid = threadIdx.x;

  if (b < 256) {
    const float* in;
    ushort_t* out;
    int N, bx, by;
    if (b < 192) { in = Wqkv; out = WqkvT; N = 1536; bx = b % 24; by = b / 24; }
    else         { in = Wout; out = WoT;   N = 512;  bx = (b - 192) % 8; by = (b - 192) / 8; }
    const int K = 512;
    const int n0 = bx * 64, k0 = by * 64;
    const int cr = tid >> 4;
    const int cc = (tid & 15) * 4;
#pragma unroll
    for (int p = 0; p < 4; p++) {
      int k = k0 + p * 16 + cr;
      float4 v = *(const float4*)(in + k * N + n0 + cc);
      ushort4 o; o.x = f2b(v.x); o.y = f2b(v.y); o.z = f2b(v.z); o.w = f2b(v.w);
      *(ushort4*)(tile + (p * 16 + cr) * 72 + cc) = o;
    }
    __syncthreads();
#pragma unroll
    for (int p = 0; p < 4; p++) {
      int n = n0 + p * 16 + cr;
      ushort4 v;
      v.x = tile[(cc + 0) * 72 + p * 16 + cr];
      v.y = tile[(cc + 1) * 72 + p * 16 + cr];
      v.z = tile[(cc + 2) * 72 + p * 16 + cr];
      v.w = tile[(cc + 3) * 72 + p * 16 + cr];
      *(ushort4*)(out + n * K + k0 + cc) = v;
    }
    return;
  }

  if (b >= 385) {
    // x -> bf16 (row-major, same RNE cvt the GEMM applied per-tile before)
    const int base = (b - 385) * 2048 + tid * 8;
    float4 v0 = *(const float4*)(x + base);
    float4 v1 = *(const float4*)(x + base + 4);
    s16x8 o;
    o[0] = (short)f2b_hw(v0.x); o[1] = (short)f2b_hw(v0.y);
    o[2] = (short)f2b_hw(v0.z); o[3] = (short)f2b_hw(v0.w);
    o[4] = (short)f2b_hw(v1.x); o[5] = (short)f2b_hw(v1.y);
    o[6] = (short)f2b_hw(v1.z); o[7] = (short)f2b_hw(v1.w);
    *(s16x8*)(xbf + base) = o;
    return;
  }

  // fold: one wave per c-row
  const int w = tid >> 6, lane = tid & 63;
  const int c = (b - 256) * 4 + w;
  if (c > 512) return;
  float a[8];
  const float* src = (c < 512) ? (Wqkv + c * 1536 + lane * 8) : (bq + lane * 8);
  float4 a0 = *(const float4*)(src);
  float4 a1 = *(const float4*)(src + 4);
  a[0]=a0.x; a[1]=a0.y; a[2]=a0.z; a[3]=a0.w;
  a[4]=a1.x; a[5]=a1.y; a[6]=a1.z; a[7]=a1.w;

  float s[16];
#pragma unroll
  for (int j = 0; j < 16; j++) s[j] = 0.f;
#pragma unroll
  for (int i = 0; i < 8; i++) {
    const float* wp = Wod + (lane * 8 + i) * 16;
#pragma unroll
    for (int j = 0; j < 16; j++) s[j] += a[i] * wp[j];
  }
#pragma unroll
  for (int mask = 1; mask < 64; mask <<= 1)
#pragma unroll
    for (int j = 0; j < 16; j++) s[j] += __shfl_xor(s[j], mask);

  if (lane < 16) {
    if (c < 512) Wcomb[c * 16 + lane] = s[lane];
    else         bcomb[lane] = s[lane] + bod[lane];
  }
}

// ------- merged qkv GEMM + od: blocks [0,384) gemm, [384,896) od -------
// BK=64 via [ks][rows][32] sub-tiled LDS: gload_lds dests stay linear per
// wave (no padding — m173), frag reads keep the proven 64B-stride banking,
// barriers per K-loop halve (16 -> 8 iters).
__global__ __launch_bounds__(256) void qkv_od_kernel(
    const float* __restrict__ x, const ushort_t* __restrict__ xbf,
    const ushort_t* __restrict__ WT,
    const float* __restrict__ bqkv,
    const float* __restrict__ Wcomb, const float* __restrict__ bcomb,
    const int* __restrict__ lenp,
    ushort_t* __restrict__ Qh, ushort_t* __restrict__ Kh, ushort_t* __restrict__ VT,
    float* __restrict__ params)
{
  const int blk = blockIdx.x;
  const int tid = threadIdx.x;

  if (blk >= 384) {
    // ---- od path ----
    const int w = tid >> 6, lane = tid & 63;
    const int m = (blk - 384) * 4 + w;   // 0..2047
    int li = lenp[0];
    float len = (li > 0 && li < 1048576) ? (float)li : 1024.0f;

    const float* qp = x + m * 512 + lane * 8;
    float q[8];
    float4 qa = *(const float4*)(qp);
    float4 qb = *(const float4*)(qp + 4);
    q[0]=qa.x; q[1]=qa.y; q[2]=qa.z; q[3]=qa.w;
    q[4]=qb.x; q[5]=qb.y; q[6]=qb.z; q[7]=qb.w;

    float s[16];
#pragma unroll
    for (int j = 0; j < 16; j++) s[j] = 0.f;
#pragma unroll
    for (int i = 0; i < 8; i++) {
      const float* wp = Wcomb + (lane * 8 + i) * 16;
#pragma unroll
      for (int j = 0; j < 16; j++) s[j] += q[i] * wp[j];
    }
#pragma unroll
    for (int mask = 1; mask < 64; mask <<= 1)
#pragma unroll
      for (int j = 0; j < 16; j++) s[j] += __shfl_xor(s[j], mask);

    if (lane < 8) {
      int h = lane;
      int bb = m >> 10, t = m & 1023;
      float odo = s[h] + bcomb[h];
      float odd = s[8 + h] + bcomb[8 + h];
      float offset = tanhf(odo) * len;
      float dur = len / (1.f + expf(-odd));
      float anchor = (float)t + offset;
      float start = anchor - dur, end = anchor + dur;
      float bl = floorf(start), br = ceilf(end);
      float al = floorf(anchor);
      float da = anchor - al;
      float* pp = params + ((bb * 8 + h) * 1024 + t) * 6;
      pp[0] = bl; pp[1] = br; pp[2] = al;
      pp[3] = bl - start; pp[4] = end - br; pp[5] = da;
    }
    return;
  }

  // ---- qkv gemm path (BK=64) ----
  __shared__ __align__(16) ushort_t As[2 * 2048];   // [ks][64][32]
  __shared__ __align__(16) ushort_t Bs[2 * 4096];   // [ks][128][32]
  const int lane = tid & 63, w = tid >> 6;
  const int wr = w >> 1, wc = w & 1;          // wave tile 32x64
  const int quad = lane >> 4, l16 = lane & 15;
  const int bx = blk % 12, by = blk / 12;
  const int m0 = by * 64, n0 = bx * 128;

  f32x4 acc[2][4];
#pragma unroll
  for (int i = 0; i < 2; i++)
#pragma unroll
    for (int j = 0; j < 4; j++) acc[i][j] = f32x4{0.f, 0.f, 0.f, 0.f};

  const int idx = tid * 8;
  const int ra = idx >> 5, ca = idx & 31;     // row 0..63, col 0..31 per subtile
  const int wbase = w << 10;                  // wave-uniform LDS byte base
  const ushort_t* ga  = xbf + (m0 + ra) * 512 + ca;
  const ushort_t* gb0 = WT + (n0 + ra) * 512 + ca;        // B rows 0..63
  const ushort_t* gb1 = WT + (n0 + 64 + ra) * 512 + ca;   // B rows 64..127

  for (int k0 = 0; k0 < 512; k0 += 64) {
    __syncthreads();                          // prev frag reads done
#pragma unroll
    for (int ks = 0; ks < 2; ks++) {
      gload_lds16(ga  + k0 + ks * 32, (char*)As + ks * 4096 + wbase);
      gload_lds16(gb0 + k0 + ks * 32, (char*)Bs + ks * 8192 + wbase);
      gload_lds16(gb1 + k0 + ks * 32, (char*)Bs + ks * 8192 + 4096 + wbase);
    }
    __syncthreads();                          // drains vmcnt -> tiles ready

#pragma unroll
    for (int ks = 0; ks < 2; ks++) {
      s16x8 af[2], bfr[4];
#pragma unroll
      for (int mt = 0; mt < 2; mt++)
        af[mt] = *(const s16x8*)(As + ks * 2048 + (wr * 32 + mt * 16 + l16) * 32 + quad * 8);
#pragma unroll
      for (int nt = 0; nt < 4; nt++)
        bfr[nt] = *(const s16x8*)(Bs + ks * 4096 + (wc * 64 + nt * 16 + l16) * 32 + quad * 8);
#pragma unroll
      for (int mt = 0; mt < 2; mt++)
#pragma unroll
        for (int nt = 0; nt < 4; nt++)
          acc[mt][nt] = MFMA32(af[mt], bfr[nt], acc[mt][nt]);
    }
  }

#pragma unroll
  for (int nt = 0; nt < 4; nt++) {
    int c = n0 + wc * 64 + nt * 16 + l16;
    float bias = bqkv[c];
    int which = c >> 9;
    int e = c & 511;
    int h = e >> 6, d = e & 63;
#pragma unroll
    for (int mt = 0; mt < 2; mt++) {
      int mbase = m0 + wr * 32 + mt * 16 + quad * 4;
      int bb = mbase >> 10, t = mbase & 1023;
      int bh = bb * 8 + h;
      if (which == 2) {
        ushort4 pk;
        pk.x = f2b(acc[mt][nt][0] + bias);
        pk.y = f2b(acc[mt][nt][1] + bias);
        pk.z = f2b(acc[mt][nt][2] + bias);
        pk.w = f2b(acc[mt][nt][3] + bias);
        *(ushort4*)(VT + (bh * 64 + d) * 1024 + t) = pk;
      } else {
        ushort_t* dst = (which == 0) ? Qh : Kh;
        float sc = (which == 0) ? 0.125f : 1.0f;
#pragma unroll
        for (int rr = 0; rr < 4; rr++)
          dst[(bh * 1024 + t + rr) * 64 + d] = f2b((acc[mt][nt][rr] + bias) * sc);
      }
    }
  }
}

// ------- attention v8: v7 + MFMA32 S-step + 3 blocks/CU -------
// 512 threads = 8 waves: wq = w>>2 picks Q-row group (mrow + wq*16), wc = w&3
// the col-quarter; both groups share each staged K/V tile. S^T now 2 chained
// MFMA32 (b128 LDS reads, v5-validated fragment mapping) instead of 4 chained
// MFMA16 -> shorter latency chain, half the K-frag ds_reads. launch_bounds
// (512,6) -> 3 blocks/CU (24 waves, 1.5x TLP; LDS 3x36.9=110.7 KB fits).
__global__ __launch_bounds__(512, 6) void attn_kernel(
    const ushort_t* __restrict__ Qh, const ushort_t* __restrict__ Kh,
    const ushort_t* __restrict__ VT, const float* __restrict__ params,
    ushort_t* __restrict__ Oh)
{
  constexpr int TS = 64 * 72;                   // one K or V tile (elems)
  __shared__ __align__(16) ushort_t KV[4 * TS]; // [p][K|V], 36.9 KB; merge overlay after loop
  __shared__ float band[16];                    // per-wave lo/hi for union

  const int tid = threadIdx.x;
  const int lane = tid & 63, w = tid >> 6;
  const int wq = w >> 2;                        // Q-row group 0/1
  const int wc = w & 3;                         // col-quarter
  const int quad = lane >> 4, l16 = lane & 15;
  const int bh = blockIdx.x;
  const int mrow = blockIdx.y * 32;
  const int qidx = mrow + wq * 16 + l16;        // this lane's Q row

  // params per lane: row q (quads redundant by construction)
  const float* ppl = params + (bh * 1024 + qidx) * 6;
  float bl = ppl[0], br = ppl[1], al = ppl[2];
  float wl = ppl[3], wr2 = ppl[4], da = ppl[5];
  bool empty = (br < 0.f) || (bl > 1023.f);
  float lo = empty ? 0.f    : fmaxf(bl, 0.f);
  float hi = empty ? 1023.f : fminf(br, 1023.f);
#pragma unroll
  for (int mask = 1; mask < 16; mask <<= 1) {
    lo = fminf(lo, __shfl_xor(lo, mask));
    hi = fmaxf(hi, __shfl_xor(hi, mask));
  }
  if (lane == 0) { band[w * 2] = lo; band[w * 2 + 1] = hi; }
  __syncthreads();
  float blo = band[0], bhi = band[1];
#pragma unroll
  for (int i = 1; i < 8; i++) {
    blo = fminf(blo, band[i * 2]);
    bhi = fmaxf(bhi, band[i * 2 + 1]);
  }
  const int tlo = ((int)blo) >> 6, thi = ((int)bhi) >> 6;   // block-uniform

  // Q fragments (B-operand, K=32): bq_i[k=quad*8+j] = Q[q][i*32+quad*8+j]
  const ushort_t* qrow = Qh + (bh * 1024 + qidx) * 64;
  s16x8 bq0 = *(const s16x8*)(qrow + quad * 8);
  s16x8 bq1 = *(const s16x8*)(qrow + 32 + quad * 8);

  float lr = 0.f;
  f32x4 Oacc[4];
#pragma unroll
  for (int g = 0; g < 4; g++) Oacc[g] = f32x4{0.f, 0.f, 0.f, 0.f};

  // staging: thread -> row tid>>3 (0..63), 8-elem segment (tid&7)*8
  const int srow = tid >> 3, sseg = (tid & 7) * 8;
  const ushort_t* kgb = Kh + (bh * 1024 + srow) * 64 + sseg;   // + r0*64
  const ushort_t* vgb = VT + (bh * 64 + srow) * 1024 + sseg;   // + r0

  s16x8 kr, vr;
  {
    const int r0 = tlo * 64;
    kr = *(const s16x8*)(kgb + r0 * 64);
    vr = *(const s16x8*)(vgb + r0);
  }
  {
    ushort_t* Kt = KV;
    ushort_t* Vt = KV + TS;
    *(s16x8*)(Kt + srow * 72 + sseg) = kr;
    *(s16x8*)(Vt + srow * 72 + sseg) = vr;
  }
  __syncthreads();

  for (int tt = tlo; tt <= thi; tt++) {
    const int p = (tt - tlo) & 1;
    ushort_t* Ktp = KV + p * 2 * TS;
    ushort_t* Vtp = KV + p * 2 * TS + TS;
    const int r0 = tt * 64;
    const bool more = (tt + 1 <= thi);

    if (more) {                          // next tile's global loads in flight
      const int r1 = (tt + 1) * 64;
      kr = *(const s16x8*)(kgb + r1 * 64);
      vr = *(const s16x8*)(vgb + r1);
    }

    // S^T = K.Q^T over this wave's 16 K-cols: 2 chained MFMA32
    const ushort_t* krow = Ktp + (wc * 16 + l16) * 72;
    s16x8 ak0 = *(const s16x8*)(krow + quad * 8);
    s16x8 ak1 = *(const s16x8*)(krow + 32 + quad * 8);
    f32x4 z = {0.f, 0.f, 0.f, 0.f};
    z = MFMA32(ak0, bq0, z);             // D[kc][q], kc = wc*16 + quad*4+rr
    z = MFMA32(ak1, bq1, z);

    // softmax: lane handles its q row, kc = cbase + quad*4 + rr
    const int cbase = r0 + wc * 16;
    const float c0f = (float)cbase, c1f = c0f + 15.f;
    bool f = (bl < c0f) && (br > c1f) && ((al + 1.f < c0f) || (al > c1f));
    s16x4 pt;
    if (__all((int)f)) {
#pragma unroll
      for (int rr = 0; rr < 4; rr++) {
        float pv = __expf(z[rr]);
        lr += pv;
        pt[rr] = (short)f2b_hw(pv);
      }
    } else {
#pragma unroll
      for (int rr = 0; rr < 4; rr++) {
        float cf = (float)(cbase + quad * 4 + rr);
        float s = z[rr];                 // includes 0.125 via Qh pre-scale
        float wgt = 1.f;
        wgt += (cf == bl) ? wl : 0.f;
        wgt += (cf == br) ? wr2 : 0.f;
        wgt += (cf == al + 1.f) ? da : 0.f;
        wgt += (cf == al) ? (1.f - da) : 0.f;
        s *= wgt;
        s = (cf < bl || cf > br) ? -30.f : s;
        float pv = __expf(s);
        lr += pv;
        pt[rr] = (short)f2b_hw(pv);
      }
    }

    // O^T = V^T.P^T : A = V^T frag (m=d local, k=kc local), B = pt (register P!)
#pragma unroll
    for (int g = 0; g < 4; g++) {
      s16x4 av = *(const s16x4*)(Vtp + (g * 16 + l16) * 72 + wc * 16 + quad * 4);
      Oacc[g] = MFMA16(av, pt, Oacc[g]); // D[d][q]
    }

    if (more) {                          // write next tile, ONE barrier per tile
      ushort_t* Ktn = KV + (p ^ 1) * 2 * TS;
      ushort_t* Vtn = KV + (p ^ 1) * 2 * TS + TS;
      *(s16x8*)(Ktn + srow * 72 + sseg) = kr;
      *(s16x8*)(Vtn + srow * 72 + sseg) = vr;
      __syncthreads();
    }
  }

  // row-sum: each quad covered distinct kc -> reduce across quads
  lr += __shfl_xor(lr, 16);
  lr += __shfl_xor(lr, 32);

  // merge scratch overlays dead staging LDS (barrier-separated)
  __syncthreads();
  float* Om  = (float*)KV;               // [w][16 q][65]
  float* lwf = Om + 8 * 16 * 65;         // [w][16 q]
#pragma unroll
  for (int g = 0; g < 4; g++)
#pragma unroll
    for (int rr = 0; rr < 4; rr++)
      Om[(w * 16 + l16) * 65 + g * 16 + quad * 4 + rr] = Oacc[g][rr];
  if (quad == 0) lwf[w * 16 + l16] = lr;
  __syncthreads();

  // merge 4 col-quarter partials per Q-group: 32x64 elems / 512 thr
  const int bb = bh >> 3, h = bh & 7;
  {
    int e = tid;                          // 2048 elems, 512 threads, 4 each
#pragma unroll
    for (int it = 0; it < 4; it++, e += 512) {
      int r = e >> 6, col = e & 63;       // r 0..31
      int p0 = (r >> 4) * 4, rl = r & 15;
      float lg = lwf[(p0 + 0) * 16 + rl] + lwf[(p0 + 1) * 16 + rl]
               + lwf[(p0 + 2) * 16 + rl] + lwf[(p0 + 3) * 16 + rl];
      float o  = Om[((p0 + 0) * 16 + rl) * 65 + col] + Om[((p0 + 1) * 16 + rl) * 65 + col]
               + Om[((p0 + 2) * 16 + rl) * 65 + col] + Om[((p0 + 3) * 16 + rl) * 65 + col];
      int t = mrow + r;
      Oh[((bb << 10) + t) * 512 + h * 64 + col] = f2b_hw(o / lg);
    }
  }
}

// ------- out GEMM: 64x64 tiles, BK=64, grid (8,32)=256 blocks -------
__global__ __launch_bounds__(256) void out_gemm_kernel(
    const ushort_t* __restrict__ Oh, const ushort_t* __restrict__ WT,
    const float* __restrict__ bout, float* __restrict__ outp)
{
  __shared__ __align__(16) ushort_t As[2 * 2048];   // [ks][64][32]
  __shared__ __align__(16) ushort_t Bs[2 * 2048];   // [ks][64][32]
  const int tid = threadIdx.x;
  const int lane = tid & 63, w = tid >> 6;
  const int wr = w >> 1, wc = w & 1;          // wave tile 32x32
  const int quad = lane >> 4, l16 = lane & 15;
  const int m0 = blockIdx.y * 64, n0 = blockIdx.x * 64;

  f32x4 acc[2][2];
#pragma unroll
  for (int i = 0; i < 2; i++)
#pragma unroll
    for (int j = 0; j < 2; j++) acc[i][j] = f32x4{0.f, 0.f, 0.f, 0.f};

  const int idx = tid * 8;
  const int ra = idx >> 5, ca = idx & 31;
  const int wbase = w << 10;
  const ushort_t* ga = Oh + (m0 + ra) * 512 + ca;
  const ushort_t* gb = WT + (n0 + ra) * 512 + ca;

  for (int k0 = 0; k0 < 512; k0 += 64) {
    __syncthreads();
#pragma unroll
    for (int ks = 0; ks < 2; ks++) {
      gload_lds16(ga + k0 + ks * 32, (char*)As + ks * 4096 + wbase);
      gload_lds16(gb + k0 + ks * 32, (char*)Bs + ks * 4096 + wbase);
    }
    __syncthreads();

#pragma unroll
    for (int ks = 0; ks < 2; ks++) {
      s16x8 af[2], bfr[2];
#pragma unroll
      for (int mt = 0; mt < 2; mt++)
        af[mt] = *(const s16x8*)(As + ks * 2048 + (wr * 32 + mt * 16 + l16) * 32 + quad * 8);
#pragma unroll
      for (int nt = 0; nt < 2; nt++)
        bfr[nt] = *(const s16x8*)(Bs + ks * 2048 + (wc * 32 + nt * 16 + l16) * 32 + quad * 8);
#pragma unroll
      for (int mt = 0; mt < 2; mt++)
#pragma unroll
        for (int nt = 0; nt < 2; nt++)
          acc[mt][nt] = MFMA32(af[mt], bfr[nt], acc[mt][nt]);
    }
  }

#pragma unroll
  for (int nt = 0; nt < 2; nt++) {
    int c = n0 + wc * 32 + nt * 16 + l16;
    float bias = bout[c];
#pragma unroll
    for (int mt = 0; mt < 2; mt++) {
#pragma unroll
      for (int rr = 0; rr < 4; rr++) {
        int m = m0 + wr * 32 + mt * 16 + quad * 4 + rr;
        outp[m * 512 + c] = acc[mt][nt][rr] + bias;
      }
    }
  }
}

extern "C" void kernel_launch(void* const* d_in, const int* in_sizes, int n_in,
                              void* d_out, int out_size, void* d_ws, size_t ws_size,
                              hipStream_t stream)
{
  const float* x    = (const float*)d_in[0];
  const float* Wqkv = (const float*)d_in[1];
  const float* bqkv = (const float*)d_in[2];
  const float* Wod  = (const float*)d_in[3];
  const float* bod  = (const float*)d_in[4];
  const float* Wout = (const float*)d_in[5];
  const float* bout = (const float*)d_in[6];
  const int* lenp   = (const int*)d_in[7];

  char* ws = (char*)d_ws;
  ushort_t* WqkvT  = (ushort_t*)(ws);                  // 1536x512 bf16
  ushort_t* WoT    = (ushort_t*)(ws + 1572864);        // 512x512 bf16
  ushort_t* Qh     = (ushort_t*)(ws + 4194304);        // 16x1024x64 bf16 (pre-scaled 0.125)
  ushort_t* Kh     = (ushort_t*)(ws + 6291456);        // 16x1024x64 bf16
  ushort_t* VT     = (ushort_t*)(ws + 8388608);        // 16x64x1024 bf16
  ushort_t* Oh     = (ushort_t*)(ws + 10485760);       // 2048x512 bf16
  float*    Wcomb  = (float*)(ws + 12582912);          // 512x16 f32
  float*    bcomb  = (float*)(ws + 12615680);          // 16 f32
  float*    params = (float*)(ws + 12615744);          // 16x1024x6 f32
  ushort_t* xbf    = (ushort_t*)(ws + 13008960);       // 2048x512 bf16

  prep_kernel<<<897, 256, 0, stream>>>(Wqkv, bqkv, Wod, bod, Wout, x,
                                       WqkvT, WoT, Wcomb, bcomb, xbf);
  qkv_od_kernel<<<896, 256, 0, stream>>>(x, xbf, WqkvT, bqkv, Wcomb, bcomb, lenp,
                                         Qh, Kh, VT, params);
  attn_kernel<<<dim3(16, 32), 512, 0, stream>>>(Qh, Kh, VT, params, Oh);
  out_gemm_kernel<<<dim3(8, 32), 256, 0, stream>>>(Oh, WoT, bout, (float*)d_out);
}